// Round 1
// baseline (150.501 us; speedup 1.0000x reference)
//
#include <hip/hip_runtime.h>
#include <math.h>

// Problem constants (FlexAttentionWithRoPE): B=2,H=16,L=2048,D=64,P=2,F=32
constexpr int B_ = 2, H_ = 16, L_ = 2048, D_ = 64, F_ = 32;
constexpr int BH_ = B_ * H_;
constexpr float SCALE_LOG2E = 0.125f * 1.44269504088896340736f; // (1/sqrt(D)) * log2(e)

using half8  = __attribute__((ext_vector_type(8))) _Float16;
using floatx4 = __attribute__((ext_vector_type(4))) float;

// ---------------------------------------------------------------------------
// Prepass: theta = pos . freqs ; rope(Q), rope(K) -> f16 ; V -> f16 transposed
// to [BH][D][L] so the flash kernel can stage V^T tiles with coalesced loads.
// One block = 64 consecutive rows (one (b,h), one 64-row l-tile). 4 thr/row.
// ---------------------------------------------------------------------------
__global__ __launch_bounds__(256) void rope_v_prepass(
    const float* __restrict__ q, const float* __restrict__ k,
    const float* __restrict__ v, const float* __restrict__ pos,
    const float* __restrict__ freqs,
    _Float16* __restrict__ qr, _Float16* __restrict__ kr,
    _Float16* __restrict__ vt) {
  __shared__ _Float16 vls[64][66];   // stride 66 f16 breaks transpose-read bank aliasing

  const int tid  = threadIdx.x;
  const int r0   = blockIdx.x * 64;      // first global row of this block
  const int lrow = tid >> 2;             // 0..63 (row within block)
  const int j    = tid & 3;              // quarter: f = j*8..j*8+7
  const int row  = r0 + lrow;            // global row in [0, B*H*L)
  const int l    = row % L_;
  const int h    = (row / L_) % H_;
  const int b    = row / (H_ * L_);

  const float p0 = pos[(b * L_ + l) * 2 + 0];
  const float p1 = pos[(b * L_ + l) * 2 + 1];

  float c[8], s[8];
  #pragma unroll
  for (int i = 0; i < 8; ++i) {
    const int f = j * 8 + i;
    const float th = p0 * freqs[(h * F_ + f) * 2 + 0] +
                     p1 * freqs[(h * F_ + f) * 2 + 1];
    c[i] = cosf(th);
    s[i] = sinf(th);
  }

  const float* qrow = q + (size_t)row * D_;
  const float* krow = k + (size_t)row * D_;

  {
    float x1[8], x2[8];
    *(float4*)(x1)     = *(const float4*)(qrow + j * 8);
    *(float4*)(x1 + 4) = *(const float4*)(qrow + j * 8 + 4);
    *(float4*)(x2)     = *(const float4*)(qrow + j * 8 + 32);
    *(float4*)(x2 + 4) = *(const float4*)(qrow + j * 8 + 36);
    half8 o1, o2;
    #pragma unroll
    for (int i = 0; i < 8; ++i) {
      o1[i] = (_Float16)(x1[i] * c[i] - x2[i] * s[i]);
      o2[i] = (_Float16)(x2[i] * c[i] + x1[i] * s[i]);
    }
    *(half8*)(qr + (size_t)row * D_ + j * 8)      = o1;
    *(half8*)(qr + (size_t)row * D_ + 32 + j * 8) = o2;
  }
  {
    float x1[8], x2[8];
    *(float4*)(x1)     = *(const float4*)(krow + j * 8);
    *(float4*)(x1 + 4) = *(const float4*)(krow + j * 8 + 4);
    *(float4*)(x2)     = *(const float4*)(krow + j * 8 + 32);
    *(float4*)(x2 + 4) = *(const float4*)(krow + j * 8 + 36);
    half8 o1, o2;
    #pragma unroll
    for (int i = 0; i < 8; ++i) {
      o1[i] = (_Float16)(x1[i] * c[i] - x2[i] * s[i]);
      o2[i] = (_Float16)(x2[i] * c[i] + x1[i] * s[i]);
    }
    *(half8*)(kr + (size_t)row * D_ + j * 8)      = o1;
    *(half8*)(kr + (size_t)row * D_ + 32 + j * 8) = o2;
  }

  // V: load f32 coalesced -> LDS f16 -> write transposed [D][L] coalesced
  const float* vrow = v + (size_t)row * D_;
  #pragma unroll
  for (int i4 = 0; i4 < 4; ++i4) {
    float4 vv = *(const float4*)(vrow + j * 16 + i4 * 4);
    vls[lrow][j * 16 + i4 * 4 + 0] = (_Float16)vv.x;
    vls[lrow][j * 16 + i4 * 4 + 1] = (_Float16)vv.y;
    vls[lrow][j * 16 + i4 * 4 + 2] = (_Float16)vv.z;
    vls[lrow][j * 16 + i4 * 4 + 3] = (_Float16)vv.w;
  }
  __syncthreads();
  const int d  = tid >> 2;   // 0..63 (output d-row)
  const int jj = tid & 3;    // 16-wide l chunk
  const int bh = b * H_ + h;
  half8 w0, w1;
  #pragma unroll
  for (int i = 0; i < 8; ++i) {
    w0[i] = vls[jj * 16 + i][d];
    w1[i] = vls[jj * 16 + 8 + i][d];
  }
  const size_t vtoff = ((size_t)bh * D_ + d) * L_ + (size_t)(r0 % L_) + jj * 16;
  *(half8*)(vt + vtoff)     = w0;
  *(half8*)(vt + vtoff + 8) = w1;
}

// ---------------------------------------------------------------------------
// Flash attention: 4 waves/block, 64 Q-rows/block (16 per wave), KVBLK=64.
// mfma_f32_16x16x32_f16. Online softmax, f32 accumulators.
// LDS tiles XOR-swizzled: byte ^= (row&7)<<4 (G4: defeat 128B-stride conflicts).
// ---------------------------------------------------------------------------
__global__ __launch_bounds__(256) void flash_attn(
    const _Float16* __restrict__ qr, const _Float16* __restrict__ kr,
    const _Float16* __restrict__ vt, float* __restrict__ out) {
  __shared__ _Float16 Kl[64 * 64];     // [kv row][d]   8 KB
  __shared__ _Float16 Vl[64 * 64];     // [d][kv row]   8 KB (from vt)
  __shared__ _Float16 Pl[4][16 * 64];  // per-wave P    8 KB

  // XCD-bijective swizzle: nwg = 1024 (divisible by 8). Each XCD gets 128
  // consecutive wg = 4 heads -> K/V working set 3 MB < 4 MB L2.
  const int nwg = gridDim.x;
  const int cpx = nwg >> 3;
  const int bid = blockIdx.x;
  const int wg  = (bid & 7) * cpx + (bid >> 3);
  const int head = wg >> 5;   // bh index
  const int qb   = wg & 31;   // q-tile index (64 rows each)

  const int tid  = threadIdx.x;
  const int wid  = tid >> 6;
  const int lane = tid & 63;
  const int lg   = lane >> 4;  // 0..3
  const int lr   = lane & 15;

  // Q fragments (A-operand layout: row = lr, k = lg*8 + j (+32))
  const _Float16* qbase =
      qr + ((size_t)head * L_ + (size_t)qb * 64 + wid * 16 + lr) * D_;
  const half8 aq0 = *(const half8*)(qbase + lg * 8);
  const half8 aq1 = *(const half8*)(qbase + 32 + lg * 8);

  const floatx4 zero4 = {0.f, 0.f, 0.f, 0.f};
  floatx4 o[4] = {zero4, zero4, zero4, zero4};
  float m2[4]   = {-INFINITY, -INFINITY, -INFINITY, -INFINITY};
  float lsum[4] = {0.f, 0.f, 0.f, 0.f};

  const _Float16* kb = kr + (size_t)head * L_ * D_;
  const _Float16* vb = vt + (size_t)head * D_ * L_;
  _Float16* pw = &Pl[wid][0];

  for (int t = 0; t < L_ / 64; ++t) {
    __syncthreads();
    // Stage K tile [64 rows][64 d] and V^T tile [64 d][64 rows], both 8 KB.
    #pragma unroll
    for (int ci = 0; ci < 2; ++ci) {
      const int c   = tid + ci * 256;     // 0..511 chunk id (16B chunks)
      const int row = c >> 3, cc = c & 7;
      const uint4 dk =
          *(const uint4*)(kb + ((size_t)(t * 64 + row)) * D_ + cc * 8);
      const int lbyte = (row * 128 + cc * 16) ^ ((row & 7) << 4);
      *(uint4*)((char*)Kl + lbyte) = dk;
      const uint4 dv =
          *(const uint4*)(vb + (size_t)row * L_ + t * 64 + cc * 8);
      *(uint4*)((char*)Vl + lbyte) = dv;
    }
    __syncthreads();

    // QK^T: scores[16 q][64 kv] per wave, C-layout: row=lg*4+j, col=lr (+16*ct)
    floatx4 sc[4];
    #pragma unroll
    for (int ct = 0; ct < 4; ++ct) {
      floatx4 acc = zero4;
      const int krow = ct * 16 + lr;
      const int b0 = (krow * 128 + lg * 16) ^ ((krow & 7) << 4);
      const int b1 = (krow * 128 + 64 + lg * 16) ^ ((krow & 7) << 4);
      const half8 bk0 = *(const half8*)((const char*)Kl + b0);
      const half8 bk1 = *(const half8*)((const char*)Kl + b1);
      acc = __builtin_amdgcn_mfma_f32_16x16x32_f16(aq0, bk0, acc, 0, 0, 0);
      acc = __builtin_amdgcn_mfma_f32_16x16x32_f16(aq1, bk1, acc, 0, 0, 0);
      sc[ct] = acc;
    }

    // scale into base-2 domain
    #pragma unroll
    for (int ct = 0; ct < 4; ++ct)
      #pragma unroll
      for (int jj = 0; jj < 4; ++jj)
        sc[ct][jj] *= SCALE_LOG2E;

    // online softmax (rows are distributed: row r = lg*4+jj held by 16 lanes)
    float fac[4];
    #pragma unroll
    for (int jj = 0; jj < 4; ++jj) {
      float v0 = fmaxf(fmaxf(sc[0][jj], sc[1][jj]), fmaxf(sc[2][jj], sc[3][jj]));
      v0 = fmaxf(v0, __shfl_xor(v0, 1));
      v0 = fmaxf(v0, __shfl_xor(v0, 2));
      v0 = fmaxf(v0, __shfl_xor(v0, 4));
      v0 = fmaxf(v0, __shfl_xor(v0, 8));
      const float mnew = fmaxf(m2[jj], v0);
      fac[jj] = exp2f(m2[jj] - mnew);   // first tile: exp2(-inf)=0
      m2[jj]  = mnew;
    }
    #pragma unroll
    for (int jj = 0; jj < 4; ++jj) {
      float r = 0.f;
      #pragma unroll
      for (int ct = 0; ct < 4; ++ct) {
        const float p = exp2f(sc[ct][jj] - m2[jj]);
        sc[ct][jj] = p;
        r += p;
      }
      r += __shfl_xor(r, 1);
      r += __shfl_xor(r, 2);
      r += __shfl_xor(r, 4);
      r += __shfl_xor(r, 8);
      lsum[jj] = lsum[jj] * fac[jj] + r;
      o[0][jj] *= fac[jj];
      o[1][jj] *= fac[jj];
      o[2][jj] *= fac[jj];
      o[3][jj] *= fac[jj];
    }

    // P (C-layout) -> LDS f16 (swizzled) for A-operand consumption
    #pragma unroll
    for (int ct = 0; ct < 4; ++ct) {
      #pragma unroll
      for (int jj = 0; jj < 4; ++jj) {
        const int r = lg * 4 + jj;
        const int byte = (r * 128 + (ct * 16 + lr) * 2) ^ ((r & 7) << 4);
        *(_Float16*)((char*)pw + byte) = (_Float16)sc[ct][jj];
      }
    }
    __syncthreads();   // also covers wave-internal P write->read ordering

    // PV: O[16 q][64 d] += P[16][64] * V[64][64]
    #pragma unroll
    for (int kc = 0; kc < 2; ++kc) {
      const int pbyte = (lr * 128 + kc * 64 + lg * 16) ^ ((lr & 7) << 4);
      const half8 ap = *(const half8*)((const char*)pw + pbyte);
      #pragma unroll
      for (int dt = 0; dt < 4; ++dt) {
        const int vrow = dt * 16 + lr;
        const int vbyte = (vrow * 128 + kc * 64 + lg * 16) ^ ((vrow & 7) << 4);
        const half8 bv = *(const half8*)((const char*)Vl + vbyte);
        o[dt] = __builtin_amdgcn_mfma_f32_16x16x32_f16(ap, bv, o[dt], 0, 0, 0);
      }
    }
  }

  // epilogue: normalize and store f32
  float* ob = out + ((size_t)head * L_ + (size_t)qb * 64 + wid * 16) * D_;
  #pragma unroll
  for (int dt = 0; dt < 4; ++dt) {
    #pragma unroll
    for (int jj = 0; jj < 4; ++jj) {
      const int r = lg * 4 + jj;
      ob[(size_t)r * D_ + dt * 16 + lr] = o[dt][jj] / lsum[jj];
    }
  }
}

// ---------------------------------------------------------------------------
extern "C" void kernel_launch(void* const* d_in, const int* in_sizes, int n_in,
                              void* d_out, int out_size, void* d_ws, size_t ws_size,
                              hipStream_t stream) {
  const float* q     = (const float*)d_in[0];
  const float* k     = (const float*)d_in[1];
  const float* v     = (const float*)d_in[2];
  const float* pos   = (const float*)d_in[3];
  const float* freqs = (const float*)d_in[4];
  float* out = (float*)d_out;

  // ws layout: q_rot f16 | k_rot f16 | v^T f16  (3 x 8.39 MB = 25.2 MB)
  _Float16* qr = (_Float16*)d_ws;
  _Float16* kr = qr + (size_t)BH_ * L_ * D_;
  _Float16* vt = kr + (size_t)BH_ * L_ * D_;

  const int rows = B_ * H_ * L_;            // 65536
  rope_v_prepass<<<rows / 64, 256, 0, stream>>>(q, k, v, pos, freqs, qr, kr, vt);

  const int nwg = BH_ * (L_ / 64);          // 1024
  flash_attn<<<nwg, 256, 0, stream>>>(qr, kr, vt, out);
}

// Round 3
// 87.574 us; speedup vs baseline: 1.7186x; 1.7186x over previous
//
#include <hip/hip_runtime.h>
#include <math.h>

// Problem constants (FlexAttentionWithRoPE): B=2,H=16,L=2048,D=64,P=2,F=32
constexpr int B_ = 2, H_ = 16, L_ = 2048, D_ = 64, F_ = 32;
constexpr int BH_ = B_ * H_;
constexpr float SCALE_LOG2E = 0.125f * 1.44269504088896340736f; // (1/sqrt(D))*log2(e)

using half8   = __attribute__((ext_vector_type(8))) _Float16;
using floatx16 = __attribute__((ext_vector_type(16))) float;
typedef unsigned int u32;

// ---------------------------------------------------------------------------
// Prepass: theta = pos . freqs ; rope(Q)*scale*log2e, rope(K) -> f16 ;
// V -> f16 transposed to [BH][D][L].
// ---------------------------------------------------------------------------
__global__ __launch_bounds__(256) void rope_v_prepass(
    const float* __restrict__ q, const float* __restrict__ k,
    const float* __restrict__ v, const float* __restrict__ pos,
    const float* __restrict__ freqs,
    _Float16* __restrict__ qr, _Float16* __restrict__ kr,
    _Float16* __restrict__ vt) {
  __shared__ _Float16 vls[64][66];

  const int tid  = threadIdx.x;
  const int r0   = blockIdx.x * 64;
  const int lrow = tid >> 2;
  const int j    = tid & 3;
  const int row  = r0 + lrow;
  const int l    = row % L_;
  const int h    = (row / L_) % H_;
  const int b    = row / (H_ * L_);

  const float p0 = pos[(b * L_ + l) * 2 + 0];
  const float p1 = pos[(b * L_ + l) * 2 + 1];

  float c[8], s[8];
  #pragma unroll
  for (int i = 0; i < 8; ++i) {
    const int f = j * 8 + i;
    const float th = p0 * freqs[(h * F_ + f) * 2 + 0] +
                     p1 * freqs[(h * F_ + f) * 2 + 1];
    c[i] = cosf(th);
    s[i] = sinf(th);
  }

  const float* qrow = q + (size_t)row * D_;
  const float* krow = k + (size_t)row * D_;

  {  // Q with scale*log2e folded in
    float x1[8], x2[8];
    *(float4*)(x1)     = *(const float4*)(qrow + j * 8);
    *(float4*)(x1 + 4) = *(const float4*)(qrow + j * 8 + 4);
    *(float4*)(x2)     = *(const float4*)(qrow + j * 8 + 32);
    *(float4*)(x2 + 4) = *(const float4*)(qrow + j * 8 + 36);
    half8 o1, o2;
    #pragma unroll
    for (int i = 0; i < 8; ++i) {
      o1[i] = (_Float16)((x1[i] * c[i] - x2[i] * s[i]) * SCALE_LOG2E);
      o2[i] = (_Float16)((x2[i] * c[i] + x1[i] * s[i]) * SCALE_LOG2E);
    }
    *(half8*)(qr + (size_t)row * D_ + j * 8)      = o1;
    *(half8*)(qr + (size_t)row * D_ + 32 + j * 8) = o2;
  }
  {  // K unscaled
    float x1[8], x2[8];
    *(float4*)(x1)     = *(const float4*)(krow + j * 8);
    *(float4*)(x1 + 4) = *(const float4*)(krow + j * 8 + 4);
    *(float4*)(x2)     = *(const float4*)(krow + j * 8 + 32);
    *(float4*)(x2 + 4) = *(const float4*)(krow + j * 8 + 36);
    half8 o1, o2;
    #pragma unroll
    for (int i = 0; i < 8; ++i) {
      o1[i] = (_Float16)(x1[i] * c[i] - x2[i] * s[i]);
      o2[i] = (_Float16)(x2[i] * c[i] + x1[i] * s[i]);
    }
    *(half8*)(kr + (size_t)row * D_ + j * 8)      = o1;
    *(half8*)(kr + (size_t)row * D_ + 32 + j * 8) = o2;
  }

  const float* vrow = v + (size_t)row * D_;
  #pragma unroll
  for (int i4 = 0; i4 < 4; ++i4) {
    float4 vv = *(const float4*)(vrow + j * 16 + i4 * 4);
    vls[lrow][j * 16 + i4 * 4 + 0] = (_Float16)vv.x;
    vls[lrow][j * 16 + i4 * 4 + 1] = (_Float16)vv.y;
    vls[lrow][j * 16 + i4 * 4 + 2] = (_Float16)vv.z;
    vls[lrow][j * 16 + i4 * 4 + 3] = (_Float16)vv.w;
  }
  __syncthreads();
  const int d  = tid >> 2;
  const int jj = tid & 3;
  const int bh = b * H_ + h;
  half8 w0, w1;
  #pragma unroll
  for (int i = 0; i < 8; ++i) {
    w0[i] = vls[jj * 16 + i][d];
    w1[i] = vls[jj * 16 + 8 + i][d];
  }
  const size_t vtoff = ((size_t)bh * D_ + d) * L_ + (size_t)(r0 % L_) + jj * 16;
  *(half8*)(vt + vtoff)     = w0;
  *(half8*)(vt + vtoff + 8) = w1;
}

// ---------------------------------------------------------------------------
// Flash attention, swapped-QK structure (m214 port to D=64):
//   - 4 waves/block, 32 q-rows/wave (q = lane&31), KVBLK=64
//   - QK^T computed as S^T = mfma_32x32x16(A=K, B=Q): scores lane-local
//   - softmax fully in-register; one shfl_xor(32) for max, one for sum
//   - P -> f16 B-frag via v_cvt_pkrtz + v_permlane32_swap_b32 (no LDS)
//     (vdst lanes 32-63 <-> src lanes 0-31; swap(w0,w2) yields word0+word2)
//   - PV computed as O^T = mfma(A=V^T, B=P^T): O columns lane-local
//   - defer-max (THR=8 in log2 domain)
// ---------------------------------------------------------------------------
__global__ __launch_bounds__(256, 2) void flash_attn(
    const _Float16* __restrict__ qr, const _Float16* __restrict__ kr,
    const _Float16* __restrict__ vt, float* __restrict__ out) {
  __shared__ _Float16 Kl[64 * 64];   // [kv 64][d 64] f16, st-swizzled
  __shared__ _Float16 Vl[64 * 64];   // [d 64][kv 64] f16, st-swizzled

  // XCD-bijective swizzle: nwg=512, 64 wg/XCD = 4 heads -> 2MB K/V in L2
  const int bid  = blockIdx.x;
  const int wg   = (bid & 7) * 64 + (bid >> 3);
  const int head = wg >> 4;
  const int qb   = wg & 15;

  const int tid  = threadIdx.x;
  const int wid  = tid >> 6;
  const int lane = tid & 63;
  const int ql   = lane & 31;   // this lane's q-row (within wave tile)
  const int hi   = lane >> 5;

  // Q B-frags (col=lane&31=q, k=hi*8+j), 4 chunks of d
  const _Float16* qbase =
      qr + ((size_t)head * L_ + (size_t)(qb * 128 + wid * 32 + ql)) * D_;
  half8 qf[4];
  #pragma unroll
  for (int c = 0; c < 4; ++c) qf[c] = *(const half8*)(qbase + c * 16 + hi * 8);

  floatx16 o0 = {}, o1 = {};         // O^T accum: d-chunks 0..31 / 32..63
  float m = -__builtin_inff(), lsum = 0.f;

  const _Float16* kb = kr + (size_t)head * L_ * D_;
  const _Float16* vb = vt + (size_t)head * D_ * L_;

  // hoisted swizzled LDS read offsets (same formula for Kl and Vl)
  int off0[4], off1[4];
  #pragma unroll
  for (int c = 0; c < 4; ++c) {
    off0[c] = (ql * 128 + c * 32 + hi * 16) ^ ((ql & 7) << 4);
    off1[c] = off0[c] + 32 * 128;
  }

  for (int t = 0; t < L_ / 64; ++t) {
    __syncthreads();
    // Stage K tile [64 kv][64 d] + V^T tile [64 d][64 kv]; linear dest,
    // inverse-swizzled source chunk (slot cc holds data chunk cc^(row&7)).
    #pragma unroll
    for (int ci = 0; ci < 2; ++ci) {
      const int c   = tid + ci * 256;
      const int row = c >> 3, cc = c & 7;
      const int cd  = cc ^ (row & 7);
      const uint4 dk = *(const uint4*)(kb + (size_t)(t * 64 + row) * D_ + cd * 8);
      *(uint4*)((char*)Kl + row * 128 + cc * 16) = dk;
      const uint4 dv = *(const uint4*)(vb + (size_t)row * L_ + t * 64 + cd * 8);
      *(uint4*)((char*)Vl + row * 128 + cc * 16) = dv;
    }
    __syncthreads();

    // ---- QK^T: S^T[kv][q], two 32-row tiles --------------------------------
    floatx16 s0 = {}, s1 = {};
    #pragma unroll
    for (int c = 0; c < 4; ++c) {
      const half8 k0 = *(const half8*)((const char*)Kl + off0[c]);
      const half8 k1 = *(const half8*)((const char*)Kl + off1[c]);
      s0 = __builtin_amdgcn_mfma_f32_32x32x16_f16(k0, qf[c], s0, 0, 0, 0);
      s1 = __builtin_amdgcn_mfma_f32_32x32x16_f16(k1, qf[c], s1, 0, 0, 0);
    }

    // ---- online softmax, lane-local ----------------------------------------
    float mx[16];
    #pragma unroll
    for (int r = 0; r < 16; ++r) mx[r] = fmaxf(s0[r], s1[r]);
    #pragma unroll
    for (int st = 8; st > 0; st >>= 1)
      #pragma unroll
      for (int r = 0; r < 8; ++r)
        if (r < st) mx[r] = fmaxf(mx[r], mx[r + st]);
    float pm = mx[0];
    pm = fmaxf(pm, __shfl_xor(pm, 32));

    if (!__all(pm <= m + 8.f)) {       // defer-max: rescale only on growth
      const float mn  = fmaxf(m, pm);
      const float fac = exp2f(m - mn);
      lsum *= fac;
      #pragma unroll
      for (int r = 0; r < 16; ++r) { o0[r] *= fac; o1[r] *= fac; }
      m = mn;
    }

    float sm[16];
    #pragma unroll
    for (int r = 0; r < 16; ++r) {
      s0[r] = exp2f(s0[r] - m);
      s1[r] = exp2f(s1[r] - m);
      sm[r] = s0[r] + s1[r];
    }
    #pragma unroll
    for (int st = 8; st > 0; st >>= 1)
      #pragma unroll
      for (int r = 0; r < 8; ++r)
        if (r < st) sm[r] += sm[r + st];
    float rs = sm[0];
    rs += __shfl_xor(rs, 32);
    lsum += rs;

    // ---- pack P to f16 words ------------------------------------------------
    u32 w[2][8];
    #pragma unroll
    for (int u = 0; u < 8; ++u) {
      w[0][u] = __builtin_bit_cast(u32,
                  __builtin_amdgcn_cvt_pkrtz(s0[2 * u], s0[2 * u + 1]));
      w[1][u] = __builtin_bit_cast(u32,
                  __builtin_amdgcn_cvt_pkrtz(s1[2 * u], s1[2 * u + 1]));
    }

    // ---- PV: O^T += V^T . P^T ----------------------------------------------
    #pragma unroll
    for (int tt = 0; tt < 2; ++tt) {
      #pragma unroll
      for (int kcl = 0; kcl < 2; ++kcl) {
        // B-frag (P^T): element j of lane = P^T[kv = kc*16 + hi*8 + j][q].
        // swap(a=w[4kcl], b=w[4kcl+2]): new_a = {hi0: a@hi0, hi1: b@hi0}
        //                               new_b = {hi0: a@hi1, hi1: b@hi1}
        // -> new_a = word{0,1} (kv hi*8+{0,1}), new_b = word{4,5} slot (z).
        u32 a0 = w[tt][4 * kcl + 0], b0 = w[tt][4 * kcl + 2];
        u32 a1 = w[tt][4 * kcl + 1], b1 = w[tt][4 * kcl + 3];
        asm("v_permlane32_swap_b32 %0, %1" : "+v"(a0), "+v"(b0));
        asm("v_permlane32_swap_b32 %0, %1" : "+v"(a1), "+v"(b1));
        uint4 bfw; bfw.x = a0; bfw.y = a1; bfw.z = b0; bfw.w = b1;
        const half8 pf = __builtin_bit_cast(half8, bfw);
        const int kc = tt * 2 + kcl;
        const half8 v0 = *(const half8*)((const char*)Vl + off0[kc]);
        const half8 v1 = *(const half8*)((const char*)Vl + off1[kc]);
        o0 = __builtin_amdgcn_mfma_f32_32x32x16_f16(v0, pf, o0, 0, 0, 0);
        o1 = __builtin_amdgcn_mfma_f32_32x32x16_f16(v1, pf, o1, 0, 0, 0);
      }
    }
  }

  // ---- epilogue: normalize, store f32 ---------------------------------------
  const float inv = 1.0f / lsum;
  float* ob = out + ((size_t)head * L_ + (size_t)(qb * 128 + wid * 32 + ql)) * D_;
  #pragma unroll
  for (int b = 0; b < 4; ++b) {
    float4 v0, v1;
    v0.x = o0[4 * b + 0] * inv; v0.y = o0[4 * b + 1] * inv;
    v0.z = o0[4 * b + 2] * inv; v0.w = o0[4 * b + 3] * inv;
    v1.x = o1[4 * b + 0] * inv; v1.y = o1[4 * b + 1] * inv;
    v1.z = o1[4 * b + 2] * inv; v1.w = o1[4 * b + 3] * inv;
    *(float4*)(ob + 8 * b + 4 * hi)      = v0;
    *(float4*)(ob + 32 + 8 * b + 4 * hi) = v1;
  }
}

// ---------------------------------------------------------------------------
extern "C" void kernel_launch(void* const* d_in, const int* in_sizes, int n_in,
                              void* d_out, int out_size, void* d_ws, size_t ws_size,
                              hipStream_t stream) {
  const float* q     = (const float*)d_in[0];
  const float* k     = (const float*)d_in[1];
  const float* v     = (const float*)d_in[2];
  const float* pos   = (const float*)d_in[3];
  const float* freqs = (const float*)d_in[4];
  float* out = (float*)d_out;

  _Float16* qr = (_Float16*)d_ws;
  _Float16* kr = qr + (size_t)BH_ * L_ * D_;
  _Float16* vt = kr + (size_t)BH_ * L_ * D_;

  const int rows = B_ * H_ * L_;            // 65536
  rope_v_prepass<<<rows / 64, 256, 0, stream>>>(q, k, v, pos, freqs, qr, kr, vt);

  const int nwg = BH_ * (L_ / 128);         // 512
  flash_attn<<<nwg, 256, 0, stream>>>(qr, kr, vt, out);
}

// Round 9
// 68.495 us; speedup vs baseline: 2.1973x; 1.2785x over previous
//
#include <hip/hip_runtime.h>
#include <math.h>

// Problem constants (FlexAttentionWithRoPE): B=2,H=16,L=2048,D=64,P=2,F=32
constexpr int B_ = 2, H_ = 16, L_ = 2048, D_ = 64, F_ = 32;
constexpr int BH_ = B_ * H_;
constexpr float SCALE_LOG2E = 0.125f * 1.44269504088896340736f; // (1/sqrt(D))*log2(e)
constexpr float INV_2PI = 0.15915494309189535f;

using half8   = __attribute__((ext_vector_type(8))) _Float16;
using floatx16 = __attribute__((ext_vector_type(16))) float;
using uint2v  = __attribute__((ext_vector_type(2))) unsigned int;
typedef unsigned int u32;

__device__ inline float fexp2(float x) { return __builtin_amdgcn_exp2f(x); }

// ---------------------------------------------------------------------------
// Prepass: theta = pos . freqs ; rope(Q)*scale*log2e, rope(K) -> f16 ;
// V -> f16 transposed to [BH][D][L].
// Trig: explicit range reduction to revolutions |t|<=0.5, then raw v_sin/v_cos
// (validated by R8's passing first call).
// ---------------------------------------------------------------------------
__global__ __launch_bounds__(256) void rope_v_prepass(
    const float* __restrict__ q, const float* __restrict__ k,
    const float* __restrict__ v, const float* __restrict__ pos,
    const float* __restrict__ freqs,
    _Float16* __restrict__ qr, _Float16* __restrict__ kr,
    _Float16* __restrict__ vt) {
  __shared__ _Float16 vls[64][66];

  const int tid  = threadIdx.x;
  const int r0   = blockIdx.x * 64;
  const int lrow = tid >> 2;
  const int j    = tid & 3;
  const int row  = r0 + lrow;
  const int l    = row % L_;
  const int h    = (row / L_) % H_;
  const int b    = row / (H_ * L_);

  const float p0 = pos[(b * L_ + l) * 2 + 0];
  const float p1 = pos[(b * L_ + l) * 2 + 1];

  float c[8], s[8];
  #pragma unroll
  for (int i = 0; i < 8; ++i) {
    const int f = j * 8 + i;
    const float th = p0 * freqs[(h * F_ + f) * 2 + 0] +
                     p1 * freqs[(h * F_ + f) * 2 + 1];
    float t = th * INV_2PI;       // revolutions
    t -= rintf(t);                // |t| <= 0.5 by construction
    c[i] = __builtin_amdgcn_cosf(t);
    s[i] = __builtin_amdgcn_sinf(t);
  }

  const float* qrow = q + (size_t)row * D_;
  const float* krow = k + (size_t)row * D_;

  {  // Q with scale*log2e folded in
    float x1[8], x2[8];
    *(float4*)(x1)     = *(const float4*)(qrow + j * 8);
    *(float4*)(x1 + 4) = *(const float4*)(qrow + j * 8 + 4);
    *(float4*)(x2)     = *(const float4*)(qrow + j * 8 + 32);
    *(float4*)(x2 + 4) = *(const float4*)(qrow + j * 8 + 36);
    half8 o1, o2;
    #pragma unroll
    for (int i = 0; i < 8; ++i) {
      o1[i] = (_Float16)((x1[i] * c[i] - x2[i] * s[i]) * SCALE_LOG2E);
      o2[i] = (_Float16)((x2[i] * c[i] + x1[i] * s[i]) * SCALE_LOG2E);
    }
    *(half8*)(qr + (size_t)row * D_ + j * 8)      = o1;
    *(half8*)(qr + (size_t)row * D_ + 32 + j * 8) = o2;
  }
  {  // K unscaled
    float x1[8], x2[8];
    *(float4*)(x1)     = *(const float4*)(krow + j * 8);
    *(float4*)(x1 + 4) = *(const float4*)(krow + j * 8 + 4);
    *(float4*)(x2)     = *(const float4*)(krow + j * 8 + 32);
    *(float4*)(x2 + 4) = *(const float4*)(krow + j * 8 + 36);
    half8 o1, o2;
    #pragma unroll
    for (int i = 0; i < 8; ++i) {
      o1[i] = (_Float16)(x1[i] * c[i] - x2[i] * s[i]);
      o2[i] = (_Float16)(x2[i] * c[i] + x1[i] * s[i]);
    }
    *(half8*)(kr + (size_t)row * D_ + j * 8)      = o1;
    *(half8*)(kr + (size_t)row * D_ + 32 + j * 8) = o2;
  }

  const float* vrow = v + (size_t)row * D_;
  #pragma unroll
  for (int i4 = 0; i4 < 4; ++i4) {
    float4 vv = *(const float4*)(vrow + j * 16 + i4 * 4);
    vls[lrow][j * 16 + i4 * 4 + 0] = (_Float16)vv.x;
    vls[lrow][j * 16 + i4 * 4 + 1] = (_Float16)vv.y;
    vls[lrow][j * 16 + i4 * 4 + 2] = (_Float16)vv.z;
    vls[lrow][j * 16 + i4 * 4 + 3] = (_Float16)vv.w;
  }
  __syncthreads();
  const int d  = tid >> 2;
  const int jj = tid & 3;
  const int bh = b * H_ + h;
  half8 w0, w1;
  #pragma unroll
  for (int i = 0; i < 8; ++i) {
    w0[i] = vls[jj * 16 + i][d];
    w1[i] = vls[jj * 16 + 8 + i][d];
  }
  const size_t vtoff = ((size_t)bh * D_ + d) * L_ + (size_t)(r0 % L_) + jj * 16;
  *(half8*)(vt + vtoff)     = w0;
  *(half8*)(vt + vtoff + 8) = w1;
}

// ---------------------------------------------------------------------------
// Flash attention — R8 structure (single-buffered, 2 barriers/iter, 4 waves,
// 128-row q-tile, KVBLK=128, grid 512) MINUS the two schedule-opaque
// constructs suspected of the replay race:
//   * no s_setprio regions
//   * v_permlane32_swap via the BUILTIN (hazard-recognizer-visible), not asm
//   - QK^T as S^T = mfma_32x32x16(A=K, B=Q): scores lane-local (4 tiles)
//   - softmax in-register; P->f16 via cvt_pkrtz + permlane32_swap
//   - PV as O^T = mfma(A=V^T, B=P^T); defer-max (THR=8, log2 domain)
// LDS: Kl [128 kv][64 d] XOR (row&7)<<4 ; Vl [64 d][128 kv] XOR (row&15)<<4.
// ---------------------------------------------------------------------------
__global__ __launch_bounds__(256, 2) void flash_attn(
    const _Float16* __restrict__ qr, const _Float16* __restrict__ kr,
    const _Float16* __restrict__ vt, float* __restrict__ out) {
  __shared__ _Float16 Kl[128 * 64];   // 16 KB
  __shared__ _Float16 Vl[64 * 128];   // 16 KB

  // XCD-bijective swizzle: nwg=512, 64 wg/XCD = 4 heads -> 2MB K/V in L2
  const int bid  = blockIdx.x;
  const int wg   = (bid & 7) * 64 + (bid >> 3);
  const int head = wg >> 4;
  const int qb   = wg & 15;

  const int tid  = threadIdx.x;
  const int wid  = tid >> 6;
  const int lane = tid & 63;
  const int ql   = lane & 31;   // this lane's q-row (within wave tile)
  const int hi   = lane >> 5;

  // Q B-frags (col=lane&31=q, k=hi*8+j), 4 chunks of d
  const _Float16* qbase =
      qr + ((size_t)head * L_ + (size_t)(qb * 128 + wid * 32 + ql)) * D_;
  half8 qf[4];
  #pragma unroll
  for (int c = 0; c < 4; ++c) qf[c] = *(const half8*)(qbase + c * 16 + hi * 8);

  floatx16 o0 = {}, o1 = {};         // O^T accum: d-chunks 0..31 / 32..63
  float m = -1.0e4f, lsum = 0.f;     // finite init: no +-inf ever enters exp2

  const _Float16* kb = kr + (size_t)head * L_ * D_;
  const _Float16* vb = vt + (size_t)head * D_ * L_;

  // hoisted swizzled LDS read offsets
  int koff[4], voff[8];
  #pragma unroll
  for (int c = 0; c < 4; ++c)
    koff[c] = (ql * 128 + c * 32 + hi * 16) ^ ((ql & 7) << 4);
  #pragma unroll
  for (int kc = 0; kc < 8; ++kc)
    voff[kc] = (ql * 256 + kc * 32 + hi * 16) ^ ((ql & 15) << 4);

  constexpr int NT = L_ / 128;       // 16

  for (int t = 0; t < NT; ++t) {
    __syncthreads();
    // Stage K [128 kv][64 d] and V^T [64 d][128 kv]; linear LDS slots hold
    // inverse-swizzled global chunks (slot s of row r <- chunk s^(r&mask)).
    #pragma unroll
    for (int ci = 0; ci < 4; ++ci) {
      const int c = tid + ci * 256;
      const int krw = c >> 3, kcc = c & 7, kcd = kcc ^ (krw & 7);
      const uint4 dk =
          *(const uint4*)(kb + (size_t)(t * 128 + krw) * D_ + kcd * 8);
      *(uint4*)((char*)Kl + krw * 128 + kcc * 16) = dk;
      const int vrw = c >> 4, vcc = c & 15, vcd = vcc ^ (vrw & 15);
      const uint4 dv =
          *(const uint4*)(vb + (size_t)vrw * L_ + t * 128 + vcd * 8);
      *(uint4*)((char*)Vl + vrw * 256 + vcc * 16) = dv;
    }
    __syncthreads();

    // ---- QK^T: S^T[kv][q], four 32-row tiles -------------------------------
    floatx16 s0 = {}, s1 = {}, s2 = {}, s3 = {};
    #pragma unroll
    for (int c = 0; c < 4; ++c) {
      const half8 k0 = *(const half8*)((const char*)Kl + koff[c]);
      const half8 k1 = *(const half8*)((const char*)Kl + koff[c] + 4096);
      const half8 k2 = *(const half8*)((const char*)Kl + koff[c] + 8192);
      const half8 k3 = *(const half8*)((const char*)Kl + koff[c] + 12288);
      s0 = __builtin_amdgcn_mfma_f32_32x32x16_f16(k0, qf[c], s0, 0, 0, 0);
      s1 = __builtin_amdgcn_mfma_f32_32x32x16_f16(k1, qf[c], s1, 0, 0, 0);
      s2 = __builtin_amdgcn_mfma_f32_32x32x16_f16(k2, qf[c], s2, 0, 0, 0);
      s3 = __builtin_amdgcn_mfma_f32_32x32x16_f16(k3, qf[c], s3, 0, 0, 0);
    }

    // ---- online softmax, lane-local ----------------------------------------
    float mx[16];
    #pragma unroll
    for (int r = 0; r < 16; ++r)
      mx[r] = fmaxf(fmaxf(s0[r], s1[r]), fmaxf(s2[r], s3[r]));
    #pragma unroll
    for (int st = 8; st > 0; st >>= 1)
      #pragma unroll
      for (int r = 0; r < 8; ++r)
        if (r < st) mx[r] = fmaxf(mx[r], mx[r + st]);
    float pm = mx[0];
    pm = fmaxf(pm, __shfl_xor(pm, 32));

    if (!__all(pm <= m + 8.f)) {       // defer-max: rescale only on growth
      const float mn  = fmaxf(m, pm);
      const float fac = fexp2(m - mn); // first iter: underflows to exactly 0
      lsum *= fac;
      #pragma unroll
      for (int r = 0; r < 16; ++r) { o0[r] *= fac; o1[r] *= fac; }
      m = mn;
    }

    float sm[16];
    #pragma unroll
    for (int r = 0; r < 16; ++r) {
      s0[r] = fexp2(s0[r] - m);
      s1[r] = fexp2(s1[r] - m);
      s2[r] = fexp2(s2[r] - m);
      s3[r] = fexp2(s3[r] - m);
      sm[r] = (s0[r] + s1[r]) + (s2[r] + s3[r]);
    }
    #pragma unroll
    for (int st = 8; st > 0; st >>= 1)
      #pragma unroll
      for (int r = 0; r < 8; ++r)
        if (r < st) sm[r] += sm[r + st];
    float rs = sm[0];
    rs += __shfl_xor(rs, 32);
    lsum += rs;

    // ---- pack P to f16 words ------------------------------------------------
    u32 w[4][8];
    #pragma unroll
    for (int u = 0; u < 8; ++u) {
      w[0][u] = __builtin_bit_cast(u32,
                  __builtin_amdgcn_cvt_pkrtz(s0[2 * u], s0[2 * u + 1]));
      w[1][u] = __builtin_bit_cast(u32,
                  __builtin_amdgcn_cvt_pkrtz(s1[2 * u], s1[2 * u + 1]));
      w[2][u] = __builtin_bit_cast(u32,
                  __builtin_amdgcn_cvt_pkrtz(s2[2 * u], s2[2 * u + 1]));
      w[3][u] = __builtin_bit_cast(u32,
                  __builtin_amdgcn_cvt_pkrtz(s3[2 * u], s3[2 * u + 1]));
    }

    // ---- PV: O^T += V^T . P^T ----------------------------------------------
    #pragma unroll
    for (int tt = 0; tt < 4; ++tt) {
      #pragma unroll
      for (int kcl = 0; kcl < 2; ++kcl) {
        // builtin swap: returns {new_vdst, new_src};
        // vdst lanes 32-63 <-> src lanes 0-31 (R3-verified semantics)
        const uint2v ra = __builtin_amdgcn_permlane32_swap(
            w[tt][4 * kcl + 0], w[tt][4 * kcl + 2], false, false);
        const uint2v rb = __builtin_amdgcn_permlane32_swap(
            w[tt][4 * kcl + 1], w[tt][4 * kcl + 3], false, false);
        uint4 bfw; bfw.x = ra.x; bfw.y = rb.x; bfw.z = ra.y; bfw.w = rb.y;
        const half8 pf = __builtin_bit_cast(half8, bfw);
        const int kc = tt * 2 + kcl;
        const half8 v0 = *(const half8*)((const char*)Vl + voff[kc]);
        const half8 v1 = *(const half8*)((const char*)Vl + voff[kc] + 8192);
        o0 = __builtin_amdgcn_mfma_f32_32x32x16_f16(v0, pf, o0, 0, 0, 0);
        o1 = __builtin_amdgcn_mfma_f32_32x32x16_f16(v1, pf, o1, 0, 0, 0);
      }
    }
  }

  // ---- epilogue: normalize, store f32 ---------------------------------------
  const float inv = 1.0f / lsum;
  float* ob = out + ((size_t)head * L_ + (size_t)(qb * 128 + wid * 32 + ql)) * D_;
  #pragma unroll
  for (int b = 0; b < 4; ++b) {
    float4 v0, v1;
    v0.x = o0[4 * b + 0] * inv; v0.y = o0[4 * b + 1] * inv;
    v0.z = o0[4 * b + 2] * inv; v0.w = o0[4 * b + 3] * inv;
    v1.x = o1[4 * b + 0] * inv; v1.y = o1[4 * b + 1] * inv;
    v1.z = o1[4 * b + 2] * inv; v1.w = o1[4 * b + 3] * inv;
    *(float4*)(ob + 8 * b + 4 * hi)      = v0;
    *(float4*)(ob + 32 + 8 * b + 4 * hi) = v1;
  }
}

// ---------------------------------------------------------------------------
extern "C" void kernel_launch(void* const* d_in, const int* in_sizes, int n_in,
                              void* d_out, int out_size, void* d_ws, size_t ws_size,
                              hipStream_t stream) {
  const float* q     = (const float*)d_in[0];
  const float* k     = (const float*)d_in[1];
  const float* v     = (const float*)d_in[2];
  const float* pos   = (const float*)d_in[3];
  const float* freqs = (const float*)d_in[4];
  float* out = (float*)d_out;

  _Float16* qr = (_Float16*)d_ws;
  _Float16* kr = qr + (size_t)BH_ * L_ * D_;
  _Float16* vt = kr + (size_t)BH_ * L_ * D_;

  const int rows = B_ * H_ * L_;            // 65536
  rope_v_prepass<<<rows / 64, 256, 0, stream>>>(q, k, v, pos, freqs, qr, kr, vt);

  const int nwg = BH_ * (L_ / 128);         // 512
  flash_attn<<<nwg, 256, 0, stream>>>(qr, kr, vt, out);
}